// Round 1
// baseline (267.355 us; speedup 1.0000x reference)
//
#include <hip/hip_runtime.h>
#include <math.h>

#define Bq 8
#define T 512
#define D 1024
#define R 4
#define V 2048
#define NCOL (V * R * R)        // 32768 columns of w_vocab
#define DSPLIT 16
#define DCHUNK (D / DSPLIT)     // 64 d-rows per k_core block
#define CBLK 1024               // cols per k_core block (256 thr * float4)

// ---------------------------------------------------------------------------
// K1: xbar[b][d] = sum_t x[b][t][d]   (mean scale cancels in all normalizes)
// grid (8, 32) x 256 threads; each block sums 16 t's for all 1024 d via float4
// ---------------------------------------------------------------------------
__global__ void k_xbar(const float* __restrict__ x, float* __restrict__ xbar) {
    int b   = blockIdx.x;
    int tc  = blockIdx.y;          // 32 chunks of 16 timesteps
    int tid = threadIdx.x;         // 256 -> 1024 d via float4
    const float4* xp = (const float4*)(x + ((size_t)b * T + (size_t)tc * 16) * D) + tid;
    float4 acc = make_float4(0.f, 0.f, 0.f, 0.f);
#pragma unroll
    for (int t = 0; t < 16; ++t) {
        float4 v = xp[t * (D / 4)];
        acc.x += v.x; acc.y += v.y; acc.z += v.z; acc.w += v.w;
    }
    float* dst = xbar + b * D + tid * 4;
    atomicAdd(dst + 0, acc.x);
    atomicAdd(dst + 1, acc.y);
    atomicAdd(dst + 2, acc.z);
    atomicAdd(dst + 3, acc.w);
}

// ---------------------------------------------------------------------------
// K2: part[ds][b][col] = sum_{d in chunk ds} xbar[b][d] * w_vocab[d][col]
// grid (32, 16) x 256 threads; each thread owns 4 cols (float4), 8 batches.
// Streams the full 128 MB of w_vocab exactly once.
// ---------------------------------------------------------------------------
__global__ void k_core(const float* __restrict__ wv, const float* __restrict__ xbar,
                       float* __restrict__ part) {
    __shared__ float xs[Bq * DCHUNK];  // 8 x 64 floats = 2 KB
    int tid  = threadIdx.x;
    int colb = blockIdx.x;             // 0..31
    int ds   = blockIdx.y;             // 0..15
    int d0   = ds * DCHUNK;

    if (tid < (Bq * DCHUNK / 4)) {     // 128 threads load the xbar slice
        int l  = tid * 4;
        int b  = l / DCHUNK;
        int dd = l % DCHUNK;
        *(float4*)(xs + l) = *(const float4*)(xbar + b * D + d0 + dd);
    }
    __syncthreads();

    int col = colb * CBLK + tid * 4;
    const float4* wp = (const float4*)(wv + (size_t)d0 * NCOL + col);
    float4 acc[Bq];
#pragma unroll
    for (int b = 0; b < Bq; ++b) acc[b] = make_float4(0.f, 0.f, 0.f, 0.f);

#pragma unroll 4
    for (int d = 0; d < DCHUNK; ++d) {
        float4 w = wp[(size_t)d * (NCOL / 4)];
#pragma unroll
        for (int b = 0; b < Bq; ++b) {
            float xv = xs[b * DCHUNK + d];
            acc[b].x += w.x * xv;
            acc[b].y += w.y * xv;
            acc[b].z += w.z * xv;
            acc[b].w += w.w * xv;
        }
    }

#pragma unroll
    for (int b = 0; b < Bq; ++b)
        *(float4*)(part + ((size_t)ds * Bq + b) * NCOL + col) = acc[b];
}

// ---------------------------------------------------------------------------
// K3: per (b,t): g[i][j] = sum_ds part[ds][b][i*V*R + y*R + j]; abs;
//     column-normalize over i; write Mn[b][t][i][j].
// grid 16 x 256; one thread per (b,t).
// ---------------------------------------------------------------------------
__global__ void k_gather(const float* __restrict__ part, const int* __restrict__ labels,
                         float* __restrict__ Mn) {
    int idx = blockIdx.x * 256 + threadIdx.x;  // 0..4095 == b*T + t
    int b   = idx >> 9;
    int y   = labels[idx];

    float4 g[R];
#pragma unroll
    for (int i = 0; i < R; ++i) g[i] = make_float4(0.f, 0.f, 0.f, 0.f);

    for (int ds = 0; ds < DSPLIT; ++ds) {
        const float* pb = part + ((size_t)ds * Bq + b) * NCOL + y * R;
#pragma unroll
        for (int i = 0; i < R; ++i) {
            float4 v = *(const float4*)(pb + i * (V * R));
            g[i].x += v.x; g[i].y += v.y; g[i].z += v.z; g[i].w += v.w;
        }
    }
#pragma unroll
    for (int i = 0; i < R; ++i) {
        g[i].x = fabsf(g[i].x); g[i].y = fabsf(g[i].y);
        g[i].z = fabsf(g[i].z); g[i].w = fabsf(g[i].w);
    }
    float4 cs = make_float4(g[0].x + g[1].x + g[2].x + g[3].x,
                            g[0].y + g[1].y + g[2].y + g[3].y,
                            g[0].z + g[1].z + g[2].z + g[3].z,
                            g[0].w + g[1].w + g[2].w + g[3].w);
    float4 rc = make_float4(1.f / cs.x, 1.f / cs.y, 1.f / cs.z, 1.f / cs.w);

    float* mo = Mn + (size_t)idx * 16;
#pragma unroll
    for (int i = 0; i < R; ++i) {
        float4 o = make_float4(g[i].x * rc.x, g[i].y * rc.y, g[i].z * rc.z, g[i].w * rc.w);
        *(float4*)(mo + i * 4) = o;
    }
}

// ---------------------------------------------------------------------------
// K4: single block. Phase 0: alpha/beta dots (256-way). Phase 1: per-thread
// 16-matrix chunk products. Tree-combine 32 chunks per batch (in order).
// Phase 2: v0 -> P v0 -> probs -> -log -> mean.
// ---------------------------------------------------------------------------
__global__ void k_chain(const float* __restrict__ Mn, const float* __restrict__ xbar,
                        const float* __restrict__ wa, const float* __restrict__ wb,
                        float* __restrict__ out) {
    __shared__ float mats[Bq][32][17];   // +1 pad vs 16 to break bank aliasing
    __shared__ float abp[256];
    __shared__ float lossp[Bq];
    int tid = threadIdx.x;

    // ---- phase 0: alpha/beta partial dots ----
    {
        int r   = tid & 3;
        int sel = (tid >> 2) & 1;
        int q   = (tid >> 3) & 3;
        int b   = tid >> 5;
        const float* w  = sel ? wb : wa;
        const float* xp = xbar + b * D;
        float s = 0.f;
#pragma unroll 8
        for (int d = q * 256; d < q * 256 + 256; ++d)
            s += xp[d] * w[d * R + r];
        abp[tid] = s;
    }

    // ---- phase 1: chunk products P = M_{last} ... M_{first} ----
    int b = tid >> 5;
    int c = tid & 31;
    float P[R][R];
#pragma unroll
    for (int i = 0; i < R; ++i)
#pragma unroll
        for (int j = 0; j < R; ++j) P[i][j] = (i == j) ? 1.f : 0.f;

    const float* mp = Mn + ((size_t)b * T + (size_t)c * 16) * 16;
    for (int t = 0; t < 16; ++t) {
        float4 m0 = *(const float4*)(mp + t * 16 + 0);
        float4 m1 = *(const float4*)(mp + t * 16 + 4);
        float4 m2 = *(const float4*)(mp + t * 16 + 8);
        float4 m3 = *(const float4*)(mp + t * 16 + 12);
        float M[R][R] = {{m0.x, m0.y, m0.z, m0.w},
                         {m1.x, m1.y, m1.z, m1.w},
                         {m2.x, m2.y, m2.z, m2.w},
                         {m3.x, m3.y, m3.z, m3.w}};
        float N[R][R];
#pragma unroll
        for (int i = 0; i < R; ++i)
#pragma unroll
            for (int j = 0; j < R; ++j)
                N[i][j] = M[i][0] * P[0][j] + M[i][1] * P[1][j] +
                          M[i][2] * P[2][j] + M[i][3] * P[3][j];
#pragma unroll
        for (int i = 0; i < R; ++i)
#pragma unroll
            for (int j = 0; j < R; ++j) P[i][j] = N[i][j];
    }
#pragma unroll
    for (int i = 0; i < R; ++i)
#pragma unroll
        for (int j = 0; j < R; ++j) mats[b][c][i * 4 + j] = P[i][j];
    __syncthreads();

    // ---- in-order tree combine: C_c <- C_{c+step} * C_c ----
    for (int rnd = 0; rnd < 5; ++rnd) {
        int step = 1 << rnd;
        bool act = ((c & (2 * step - 1)) == 0);
        float N2[R][R];
        if (act) {
            float A[R][R], Bm[R][R];
#pragma unroll
            for (int i = 0; i < R; ++i)
#pragma unroll
                for (int j = 0; j < R; ++j) {
                    A[i][j]  = mats[b][c + step][i * 4 + j];
                    Bm[i][j] = mats[b][c][i * 4 + j];
                }
#pragma unroll
            for (int i = 0; i < R; ++i)
#pragma unroll
                for (int j = 0; j < R; ++j)
                    N2[i][j] = A[i][0] * Bm[0][j] + A[i][1] * Bm[1][j] +
                               A[i][2] * Bm[2][j] + A[i][3] * Bm[3][j];
        }
        __syncthreads();
        if (act) {
#pragma unroll
            for (int i = 0; i < R; ++i)
#pragma unroll
                for (int j = 0; j < R; ++j) mats[b][c][i * 4 + j] = N2[i][j];
        }
        __syncthreads();
    }

    // ---- phase 2: finalize per batch ----
    if (tid < Bq) {
        int bb = tid;
        float a[R], be[R];
#pragma unroll
        for (int r = 0; r < R; ++r) {
            float sa = 0.f, sb = 0.f;
#pragma unroll
            for (int q = 0; q < 4; ++q) {
                sa += abp[(bb << 5) | (q << 3) | (0 << 2) | r];
                sb += abp[(bb << 5) | (q << 3) | (1 << 2) | r];
            }
            a[r] = sa; be[r] = sb;
        }
        float sa = fabsf(a[0]) + fabsf(a[1]) + fabsf(a[2]) + fabsf(a[3]);
        float v0[R];
#pragma unroll
        for (int r = 0; r < R; ++r) v0[r] = fabsf(a[r]) / sa;
        float v[R];
#pragma unroll
        for (int i = 0; i < R; ++i)
            v[i] = mats[bb][0][i * 4 + 0] * v0[0] + mats[bb][0][i * 4 + 1] * v0[1] +
                   mats[bb][0][i * 4 + 2] * v0[2] + mats[bb][0][i * 4 + 3] * v0[3];
        float sb = fabsf(be[0]) + fabsf(be[1]) + fabsf(be[2]) + fabsf(be[3]);
        float prob = (fabsf(be[0]) * v[0] + fabsf(be[1]) * v[1] +
                      fabsf(be[2]) * v[2] + fabsf(be[3]) * v[3]) / sb;
        lossp[bb] = -logf(prob);
    }
    __syncthreads();
    if (tid == 0) {
        float s = 0.f;
#pragma unroll
        for (int i = 0; i < Bq; ++i) s += lossp[i];
        out[0] = s * (1.f / Bq);
    }
}

extern "C" void kernel_launch(void* const* d_in, const int* in_sizes, int n_in,
                              void* d_out, int out_size, void* d_ws, size_t ws_size,
                              hipStream_t stream) {
    const float* x      = (const float*)d_in[0];   // [8,512,1024] fp32
    const int*   labels = (const int*)d_in[1];     // [8,512] int32
    const float* wa     = (const float*)d_in[2];   // [1024,4]
    const float* wb     = (const float*)d_in[3];   // [1024,4]
    const float* wv     = (const float*)d_in[4];   // [1024,32768]
    float* out = (float*)d_out;                    // scalar loss

    float* xbar = (float*)d_ws;                              // 8192 floats
    float* part = xbar + Bq * D;                             // 16*8*32768 floats = 16 MB
    float* Mn   = part + (size_t)DSPLIT * Bq * NCOL;         // 65536 floats

    hipMemsetAsync(xbar, 0, Bq * D * sizeof(float), stream);
    k_xbar<<<dim3(Bq, 32), 256, 0, stream>>>(x, xbar);
    k_core<<<dim3(NCOL / CBLK, DSPLIT), 256, 0, stream>>>(wv, xbar, part);
    k_gather<<<Bq * T / 256, 256, 0, stream>>>(part, labels, Mn);
    k_chain<<<1, 256, 0, stream>>>(Mn, xbar, wa, wb, out);
}

// Round 2
// 239.830 us; speedup vs baseline: 1.1148x; 1.1148x over previous
//
#include <hip/hip_runtime.h>
#include <math.h>

#define Bq 8
#define T 512
#define D 1024
#define R 4
#define V 2048
#define NCOL (V * R * R)        // 32768 columns of w_vocab
#define DSPLIT 16
#define DCHUNK (D / DSPLIT)     // 64 d-rows per k_core block
#define CBLK 1024               // cols per k_core block (256 thr * float4)

// ---------------------------------------------------------------------------
// K1: xbar[b][d] = sum_t x[b][t][d]   (mean scale cancels in all normalizes)
// grid (8, 32) x 256 threads; each block sums 16 t's for all 1024 d via float4
// ---------------------------------------------------------------------------
__global__ void k_xbar(const float* __restrict__ x, float* __restrict__ xbar) {
    int b   = blockIdx.x;
    int tc  = blockIdx.y;          // 32 chunks of 16 timesteps
    int tid = threadIdx.x;         // 256 -> 1024 d via float4
    const float4* xp = (const float4*)(x + ((size_t)b * T + (size_t)tc * 16) * D) + tid;
    float4 acc = make_float4(0.f, 0.f, 0.f, 0.f);
#pragma unroll
    for (int t = 0; t < 16; ++t) {
        float4 v = xp[t * (D / 4)];
        acc.x += v.x; acc.y += v.y; acc.z += v.z; acc.w += v.w;
    }
    float* dst = xbar + b * D + tid * 4;
    atomicAdd(dst + 0, acc.x);
    atomicAdd(dst + 1, acc.y);
    atomicAdd(dst + 2, acc.z);
    atomicAdd(dst + 3, acc.w);
}

// ---------------------------------------------------------------------------
// K2: part[ds][b][col] = sum_{d in chunk ds} xbar[b][d] * w_vocab[d][col]
// grid (32, 16) x 256 threads; each thread owns 4 cols (float4), 8 batches.
// Streams the full 128 MB of w_vocab exactly once. unroll 8 -> 8 KB/wave
// in flight (latency-BW product per CU is ~9 KB; 8 waves/CU -> 64 KB).
// ---------------------------------------------------------------------------
__global__ void k_core(const float* __restrict__ wv, const float* __restrict__ xbar,
                       float* __restrict__ part) {
    __shared__ float xs[Bq * DCHUNK];  // 8 x 64 floats = 2 KB
    int tid  = threadIdx.x;
    int colb = blockIdx.x;             // 0..31
    int ds   = blockIdx.y;             // 0..15
    int d0   = ds * DCHUNK;

    if (tid < (Bq * DCHUNK / 4)) {     // 128 threads load the xbar slice
        int l  = tid * 4;
        int b  = l / DCHUNK;
        int dd = l % DCHUNK;
        *(float4*)(xs + l) = *(const float4*)(xbar + b * D + d0 + dd);
    }
    __syncthreads();

    int col = colb * CBLK + tid * 4;
    const float4* wp = (const float4*)(wv + (size_t)d0 * NCOL + col);
    float4 acc[Bq];
#pragma unroll
    for (int b = 0; b < Bq; ++b) acc[b] = make_float4(0.f, 0.f, 0.f, 0.f);

#pragma unroll 8
    for (int d = 0; d < DCHUNK; ++d) {
        float4 w = wp[(size_t)d * (NCOL / 4)];
#pragma unroll
        for (int b = 0; b < Bq; ++b) {
            float xv = xs[b * DCHUNK + d];
            acc[b].x += w.x * xv;
            acc[b].y += w.y * xv;
            acc[b].z += w.z * xv;
            acc[b].w += w.w * xv;
        }
    }

#pragma unroll
    for (int b = 0; b < Bq; ++b)
        *(float4*)(part + ((size_t)ds * Bq + b) * NCOL + col) = acc[b];
}

// ---------------------------------------------------------------------------
// K3: gather + column-normalize. grid (8 b, 8 tchunk) x 256 threads.
// thread = (t_local, i): t_local = tid>>2 in [0,64), i = tid&3 (matrix row).
// 16 independent float4 loads per thread (fully unrolled -> 16 in flight),
// column sums over i via shfl_xor within the 4-lane group.
// ---------------------------------------------------------------------------
__global__ void k_gather(const float* __restrict__ part, const int* __restrict__ labels,
                         float* __restrict__ Mn) {
    int b   = blockIdx.x;
    int tc  = blockIdx.y;
    int tid = threadIdx.x;
    int tl  = tid >> 2;               // 0..63
    int i   = tid & 3;                // matrix row
    int t   = tc * 64 + tl;
    int y   = labels[b * T + t];

    const float* pb = part + (size_t)b * NCOL + (size_t)i * (V * R) + (size_t)y * R;
    float4 g = make_float4(0.f, 0.f, 0.f, 0.f);
#pragma unroll
    for (int ds = 0; ds < DSPLIT; ++ds) {
        float4 v = *(const float4*)(pb + (size_t)ds * (Bq * NCOL));
        g.x += v.x; g.y += v.y; g.z += v.z; g.w += v.w;
    }
    g.x = fabsf(g.x); g.y = fabsf(g.y); g.z = fabsf(g.z); g.w = fabsf(g.w);

    // all-reduce over the 4-lane i-group (lanes differ in bits 0..1)
    float sx = g.x, sy = g.y, sz = g.z, sw = g.w;
    sx += __shfl_xor(sx, 1); sy += __shfl_xor(sy, 1);
    sz += __shfl_xor(sz, 1); sw += __shfl_xor(sw, 1);
    sx += __shfl_xor(sx, 2); sy += __shfl_xor(sy, 2);
    sz += __shfl_xor(sz, 2); sw += __shfl_xor(sw, 2);

    float4 o = make_float4(g.x / sx, g.y / sy, g.z / sz, g.w / sw);
    *(float4*)(Mn + ((size_t)(b * T + t)) * 16 + i * 4) = o;
}

// ---------------------------------------------------------------------------
// K4: one block per batch, 64 threads (1 wave). Phase 0: alpha/beta dots.
// Phase 1: per-thread 8-matrix chunk products + 6-level in-order LDS tree.
// Phase 2: v0 -> P v0 -> prob -> atomicAdd(-log(prob)/8) into zeroed out.
// ---------------------------------------------------------------------------
__global__ void k_chain(const float* __restrict__ Mn, const float* __restrict__ xbar,
                        const float* __restrict__ wa, const float* __restrict__ wb,
                        float* __restrict__ out) {
    __shared__ float mats[64][17];    // +1 pad
    __shared__ float abp[64];
    int b   = blockIdx.x;
    int tid = threadIdx.x;            // 0..63

    // ---- phase 0: alpha/beta partial dots (8 segs x {a,b} x 4 r) ----
    {
        int r   = tid & 3;
        int sel = (tid >> 2) & 1;
        int seg = tid >> 3;           // 0..7, 128 d each
        const float* w  = sel ? wb : wa;
        const float* xp = xbar + b * D;
        float s = 0.f;
#pragma unroll 8
        for (int d = seg * 128; d < seg * 128 + 128; ++d)
            s += xp[d] * w[d * R + r];
        abp[tid] = s;
    }

    // ---- phase 1: chunk product P = M_{c*8+7} ... M_{c*8} ----
    int c = tid;
    const float* mp = Mn + ((size_t)b * T + (size_t)c * 8) * 16;
    float P[R][R];
    {
        float4 m0 = *(const float4*)(mp + 0);
        float4 m1 = *(const float4*)(mp + 4);
        float4 m2 = *(const float4*)(mp + 8);
        float4 m3 = *(const float4*)(mp + 12);
        P[0][0]=m0.x; P[0][1]=m0.y; P[0][2]=m0.z; P[0][3]=m0.w;
        P[1][0]=m1.x; P[1][1]=m1.y; P[1][2]=m1.z; P[1][3]=m1.w;
        P[2][0]=m2.x; P[2][1]=m2.y; P[2][2]=m2.z; P[2][3]=m2.w;
        P[3][0]=m3.x; P[3][1]=m3.y; P[3][2]=m3.z; P[3][3]=m3.w;
    }
#pragma unroll
    for (int t = 1; t < 8; ++t) {
        float4 m0 = *(const float4*)(mp + t * 16 + 0);
        float4 m1 = *(const float4*)(mp + t * 16 + 4);
        float4 m2 = *(const float4*)(mp + t * 16 + 8);
        float4 m3 = *(const float4*)(mp + t * 16 + 12);
        float M[R][R] = {{m0.x, m0.y, m0.z, m0.w},
                         {m1.x, m1.y, m1.z, m1.w},
                         {m2.x, m2.y, m2.z, m2.w},
                         {m3.x, m3.y, m3.z, m3.w}};
        float N[R][R];
#pragma unroll
        for (int i = 0; i < R; ++i)
#pragma unroll
            for (int j = 0; j < R; ++j)
                N[i][j] = M[i][0] * P[0][j] + M[i][1] * P[1][j] +
                          M[i][2] * P[2][j] + M[i][3] * P[3][j];
#pragma unroll
        for (int i = 0; i < R; ++i)
#pragma unroll
            for (int j = 0; j < R; ++j) P[i][j] = N[i][j];
    }
#pragma unroll
    for (int i = 0; i < R; ++i)
#pragma unroll
        for (int j = 0; j < R; ++j) mats[c][i * 4 + j] = P[i][j];
    __syncthreads();

    // ---- in-order tree combine: C_c <- C_{c+step} * C_c ----
    for (int rnd = 0; rnd < 6; ++rnd) {
        int step = 1 << rnd;
        bool act = ((c & (2 * step - 1)) == 0);
        float N2[R][R];
        if (act) {
            float A[R][R], Bm[R][R];
#pragma unroll
            for (int i = 0; i < R; ++i)
#pragma unroll
                for (int j = 0; j < R; ++j) {
                    A[i][j]  = mats[c + step][i * 4 + j];
                    Bm[i][j] = mats[c][i * 4 + j];
                }
#pragma unroll
            for (int i = 0; i < R; ++i)
#pragma unroll
                for (int j = 0; j < R; ++j)
                    N2[i][j] = A[i][0] * Bm[0][j] + A[i][1] * Bm[1][j] +
                               A[i][2] * Bm[2][j] + A[i][3] * Bm[3][j];
        }
        __syncthreads();
        if (act) {
#pragma unroll
            for (int i = 0; i < R; ++i)
#pragma unroll
                for (int j = 0; j < R; ++j) mats[c][i * 4 + j] = N2[i][j];
        }
        __syncthreads();
    }

    // ---- phase 2: finalize this batch ----
    if (tid == 0) {
        float a[R], be[R];
#pragma unroll
        for (int r = 0; r < R; ++r) {
            float sa = 0.f, sb = 0.f;
#pragma unroll
            for (int seg = 0; seg < 8; ++seg) {
                sa += abp[(seg << 3) | r];
                sb += abp[(seg << 3) | 4 | r];
            }
            a[r] = sa; be[r] = sb;
        }
        float sa = fabsf(a[0]) + fabsf(a[1]) + fabsf(a[2]) + fabsf(a[3]);
        float v0[R];
#pragma unroll
        for (int r = 0; r < R; ++r) v0[r] = fabsf(a[r]) / sa;
        float v[R];
#pragma unroll
        for (int i = 0; i < R; ++i)
            v[i] = mats[0][i * 4 + 0] * v0[0] + mats[0][i * 4 + 1] * v0[1] +
                   mats[0][i * 4 + 2] * v0[2] + mats[0][i * 4 + 3] * v0[3];
        float sb = fabsf(be[0]) + fabsf(be[1]) + fabsf(be[2]) + fabsf(be[3]);
        float prob = (fabsf(be[0]) * v[0] + fabsf(be[1]) * v[1] +
                      fabsf(be[2]) * v[2] + fabsf(be[3]) * v[3]) / sb;
        atomicAdd(out, -logf(prob) * 0.125f);
    }
}

extern "C" void kernel_launch(void* const* d_in, const int* in_sizes, int n_in,
                              void* d_out, int out_size, void* d_ws, size_t ws_size,
                              hipStream_t stream) {
    const float* x      = (const float*)d_in[0];   // [8,512,1024] fp32
    const int*   labels = (const int*)d_in[1];     // [8,512] int32
    const float* wa     = (const float*)d_in[2];   // [1024,4]
    const float* wb     = (const float*)d_in[3];   // [1024,4]
    const float* wv     = (const float*)d_in[4];   // [1024,32768]
    float* out = (float*)d_out;                    // scalar loss

    float* xbar = (float*)d_ws;                              // 8192 floats
    float* part = xbar + Bq * D;                             // 16*8*32768 floats = 16 MB
    float* Mn   = part + (size_t)DSPLIT * Bq * NCOL;         // 65536 floats

    hipMemsetAsync(xbar, 0, Bq * D * sizeof(float), stream);
    hipMemsetAsync(out, 0, sizeof(float), stream);
    k_xbar<<<dim3(Bq, 32), 256, 0, stream>>>(x, xbar);
    k_core<<<dim3(NCOL / CBLK, DSPLIT), 256, 0, stream>>>(wv, xbar, part);
    k_gather<<<dim3(Bq, T / 64), 256, 0, stream>>>(part, labels, Mn);
    k_chain<<<Bq, 64, 0, stream>>>(Mn, xbar, wa, wb, out);
}